// Round 17
// baseline (452.382 us; speedup 1.0000x reference)
//
#include <hip/hip_runtime.h>
#include <hip/hip_bf16.h>
#include <float.h>
#include <math.h>

#define DEV __device__ __forceinline__

DEV float lrelu(float x) { return x >= 0.f ? x : 0.2f * x; }

constexpr int N = 4096, KNN = 20;

typedef __attribute__((ext_vector_type(4))) float f32x4;
typedef __attribute__((ext_vector_type(8))) short s16x8;

// ---- ws layout (float offsets) ----
constexpr size_t OFF_SC1 = 0,    OFF_SH1 = 64;
constexpr size_t OFF_SC2 = 128,  OFF_SH2 = 192;
constexpr size_t OFF_SC3 = 256,  OFF_SH3 = 384;
constexpr size_t OFF_SC4 = 512,  OFF_SH4 = 768;
constexpr size_t OFF_SC5 = 1024, OFF_SH5 = 1536;
constexpr size_t OFF_X1 = 2048;                              // 64*4096
constexpr size_t OFF_X2 = OFF_X1 + (size_t)64*4096;          // 64*8192
constexpr size_t OFF_X3 = OFF_X2 + (size_t)64*8192;          // 128*16384
constexpr size_t OFF_X4 = OFF_X3 + (size_t)128*16384;        // x4 f32 [512 logical o][16384 p]
constexpr size_t OFF_A  = OFF_X4 + (size_t)256*32768;        // A splits (s2/s3), stage4 Abf + w5bf
constexpr size_t OFF_GP = OFF_A + (size_t)256*21*128;        // 4MB: gram partials [0,1MB); hi/lo splits [2MB,4MB); x3-bf16 later
constexpr size_t OFF_PM = OFF_GP + (size_t)64*128*128;       // 512*128
constexpr size_t OFF_PS = OFF_PM + (size_t)512*256;          // 512*128
constexpr size_t OFF_Z0 = OFF_PS + (size_t)512*256;          // 1024
constexpr size_t OFF_Z1 = OFF_Z0 + 1024;                     // 512
constexpr size_t OFF_Z2 = OFF_Z1 + 512;                      // 256
constexpr size_t OFF_IDX = OFF_Z2 + 256;                     // ints, 4096*20
constexpr size_t WS_NEEDED_BYTES = OFF_IDX * 4 + (size_t)N * KNN * 4;
constexpr size_t OFF_ABF = OFF_A;                            // stage-4 padded A, bf16: 8192*128
constexpr size_t OFF_W5BF = OFF_A + 524288;                  // bf16 w5 (512*256) after Abf
constexpr size_t OFF_SPLIT = OFF_GP + 524288;                // hi/lo split area (bytes [2MB,4MB) of GP)

// ---- ws-too-small sentinel ----
__global__ void k_ws_sentinel(float* out, float mb) {
  int t = threadIdx.x;
  if (t < 11) out[t] = 1.0e6f + mb;
}

// ---- bn scale/shift precompute ----
__global__ __launch_bounds__(512) void k_bn_pre(
    const float* g1, const float* b1, const float* m1, const float* v1,
    const float* g2, const float* b2, const float* m2, const float* v2,
    const float* g3, const float* b3, const float* m3, const float* v3,
    const float* g4, const float* b4, const float* m4, const float* v4,
    const float* g5, const float* b5, const float* m5, const float* v5,
    float* ws) {
  int t = threadIdx.x;
  const float* G[5] = {g1,g2,g3,g4,g5};
  const float* B[5] = {b1,b2,b3,b4,b5};
  const float* M[5] = {m1,m2,m3,m4,m5};
  const float* V[5] = {v1,v2,v3,v4,v5};
  const size_t SC[5] = {OFF_SC1,OFF_SC2,OFF_SC3,OFF_SC4,OFF_SC5};
  const size_t SH[5] = {OFF_SH1,OFF_SH2,OFF_SH3,OFF_SH4,OFF_SH5};
  const int CN[5] = {64,64,128,256,512};
  for (int s = 0; s < 5; ++s) {
    for (int i = t; i < CN[s]; i += 512) {
      float scale = G[s][i] / sqrtf(V[s][i] + 1e-5f);
      ws[SC[s] + i] = scale;
      ws[SH[s] + i] = B[s][i] - M[s][i] * scale;
    }
  }
}

// ---- stage 1 top-20 v4: 4 waves/block, hierarchical 8x8 group maxima ----
__global__ __launch_bounds__(256) void k_s1_topk(const float* x, int* idx) {
  int t = threadIdx.x;
  int lane = t & 63, wid = t >> 6;
  int i = blockIdx.x*4 + wid;
  float v[64];
  {
    #pragma clang fp contract(off)
    float xi0 = x[i], xi1 = x[N + i], xi2 = x[2*N + i];
    float sqi = xi0*xi0 + xi1*xi1 + xi2*xi2;
    #pragma unroll
    for (int u = 0; u < 64; ++u) {
      int j = u*64 + lane;
      float xj0 = x[j], xj1 = x[N+j], xj2 = x[2*N+j];
      float sqj = xj0*xj0 + xj1*xj1 + xj2*xj2;
      float p = xi0*xj0 + xi1*xj1 + xi2*xj2;
      v[u] = (2.f*p - sqi) - sqj;
    }
  }
  float gv[8]; int gu[8];
  #pragma unroll
  for (int g = 0; g < 8; ++g) {
    float m = v[g*8]; int mu = g*8;
    #pragma unroll
    for (int u2 = 1; u2 < 8; ++u2)
      if (v[g*8+u2] > m) { m = v[g*8+u2]; mu = g*8+u2; }
    gv[g] = m; gu[g] = mu;
  }
  float bv; int bu;
  bv = gv[0]; bu = gu[0];
  #pragma unroll
  for (int g = 1; g < 8; ++g) if (gv[g] > bv) { bv = gv[g]; bu = gu[g]; }
  int bi = bu*64 + lane;
  for (int k = 0; k < KNN; ++k) {
    float rv = bv; int ri = bi;
    #pragma unroll
    for (int off = 1; off < 64; off <<= 1) {
      float v2 = __shfl_xor(rv, off); int i2 = __shfl_xor(ri, off);
      if (v2 > rv || (v2 == rv && i2 < ri)) { rv = v2; ri = i2; }
    }
    if (lane == 0) idx[i*KNN + k] = ri;
    if ((ri & 63) == lane) {
      int wu = ri >> 6;
      int wg = wu >> 3;
      #pragma unroll
      for (int g = 0; g < 8; ++g) {
        if (g == wg) {
          float m = -FLT_MAX; int mu = g*8;
          #pragma unroll
          for (int u2 = 0; u2 < 8; ++u2) {
            if (g*8+u2 == wu) v[g*8+u2] = -FLT_MAX;
            float val = v[g*8+u2];
            if (val > m) { m = val; mu = g*8+u2; }
          }
          gv[g] = m; gu[g] = mu;
        }
      }
      bv = gv[0]; bu = gu[0];
      #pragma unroll
      for (int g = 1; g < 8; ++g) if (gv[g] > bv) { bv = gv[g]; bu = gu[g]; }
      bi = bu*64 + lane;
    }
  }
}

// ---- stage 1 conv ----
__global__ __launch_bounds__(256) void k_s1_conv(const float* x, const float* w1g,
                                                 const int* idx, const float* sc, const float* sh, float* x1) {
  __shared__ int idxs[64][KNN];
  __shared__ float xs[3][64];
  __shared__ float wsh[4][6];
  int t = threadIdx.x, bx = blockIdx.x, by = blockIdx.y;
  int i0 = bx * 64;
  for (int u = t; u < 64*KNN; u += 256) idxs[u/KNN][u%KNN] = idx[(size_t)(i0 + u/KNN)*KNN + u%KNN];
  for (int u = t; u < 3*64; u += 256) xs[u/64][u%64] = x[(size_t)(u/64)*N + i0 + (u%64)];
  for (int u = t; u < 24; u += 256) wsh[u/6][u%6] = w1g[(size_t)(by*4 + u/6)*6 + u%6];
  __syncthreads();
  int il = t & 63, ol = t >> 6;
  int o = by*4 + ol, i = i0 + il;
  float xi0 = xs[0][il], xi1 = xs[1][il], xi2 = xs[2][il];
  float w0 = wsh[ol][0], w1v = wsh[ol][1], w2v = wsh[ol][2];
  float w3v = wsh[ol][3], w4v = wsh[ol][4], w5v = wsh[ol][5];
  float ctr = w3v*xi0 + w4v*xi1 + w5v*xi2;
  float scale = sc[o], shift = sh[o];
  float best = -FLT_MAX;
  for (int k = 0; k < KNN; ++k) {
    int j = idxs[il][k];
    float h = w0*(x[j] - xi0) + w1v*(x[N+j] - xi1) + w2v*(x[2*N+j] - xi2) + ctr;
    h = lrelu(h*scale + shift);
    best = fmaxf(best, h);
  }
  x1[(size_t)o*N + i] = best;
}

// ---- partial Gram ----
template<int P>
__global__ __launch_bounds__(256) void k_gram_partial(const float* prev, int C, float* gp) {
  constexpr int BI = P / 16;
  __shared__ float ysh[32][P];
  int b = blockIdx.x, t = threadIdx.x;
  int R = C / gridDim.x;
  int base = b * R;
  float acc[BI][BI] = {};
  int i0 = (t >> 4) * BI, j0 = (t & 15) * BI;
  for (int r0 = 0; r0 < R; r0 += 32) {
    for (int u = t; u < 32*P; u += 256) ysh[u/P][u%P] = prev[(size_t)(base + r0 + u/P)*P + (u%P)];
    __syncthreads();
    for (int r = 0; r < 32; ++r) {
      float yi[BI], yj[BI];
      #pragma unroll
      for (int a = 0; a < BI; ++a) { yi[a] = ysh[r][i0+a]; yj[a] = ysh[r][j0+a]; }
      #pragma unroll
      for (int a = 0; a < BI; ++a)
        #pragma unroll
        for (int c = 0; c < BI; ++c) acc[a][c] += yi[a]*yj[c];
    }
    __syncthreads();
  }
  for (int a = 0; a < BI; ++a)
    for (int c = 0; c < BI; ++c)
      gp[(size_t)b*P*P + (size_t)(i0+a)*P + (j0+c)] = acc[a][c];
}

// ---- dist_topk v2: 256-thr segmented reduction + single-wave register top-k ----
template<int P>
__global__ __launch_bounds__(256) void k_dist_topk(const float* gp, int* idx, int nb) {
  constexpr int SEG = 256 / P;              // 4 for P=64, 2 for P=128
  __shared__ float gsum[SEG][P];
  __shared__ float esum[SEG][P];
  __shared__ float dsh[P];
  __shared__ float diag[P];
  int i = blockIdx.x, t = threadIdx.x;
  int c = t & (P - 1), s = t / P;
  int q = nb / SEG;
  float g = 0.f, e = 0.f;
  for (int b = s*q; b < (s+1)*q; ++b) {
    g += gp[(size_t)b*P*P + (size_t)i*P + c];
    e += gp[(size_t)b*P*P + (size_t)c*P + c];
  }
  gsum[s][c] = g; esum[s][c] = e;
  __syncthreads();
  if (t < P) {
    float gg = gsum[0][t], ee = esum[0][t];
    #pragma unroll
    for (int s2 = 1; s2 < SEG; ++s2) { gg += gsum[s2][t]; ee += esum[s2][t]; }
    diag[t] = ee;
    dsh[t] = gg;
  }
  __syncthreads();
  if (t < P) dsh[t] = (2.f*dsh[t] - diag[i]) - diag[t];
  __syncthreads();
  // single-wave register top-k (lane holds d[lane] and, for P=128, d[lane+64])
  if (t < 64) {
    int lane = t;
    float v0 = dsh[lane];
    float v1 = (P == 128) ? dsh[lane + 64] : -FLT_MAX;
    for (int k = 0; k < KNN; ++k) {
      float bv; int bi;
      if (v1 > v0) { bv = v1; bi = lane + 64; } else { bv = v0; bi = lane; }
      #pragma unroll
      for (int off = 1; off < 64; off <<= 1) {
        float v2 = __shfl_xor(bv, off); int i2 = __shfl_xor(bi, off);
        if (v2 > bv || (v2 == bv && i2 < bi)) { bv = v2; bi = i2; }
      }
      if (lane == 0) idx[i*KNN + k] = bi;
      if ((bi & 63) == lane) {
        if (bi < 64) v0 = -FLT_MAX; else v1 = -FLT_MAX;
      }
    }
  }
}

// ---- build padded-32 A hi/lo bf16 (stages 2/3, P=64): row r = o*32+kk ----
__global__ __launch_bounds__(64) void k_build_A_bf32(const float* w, const int* idx,
                                                     __hip_bfloat16* Ah, __hip_bfloat16* Al) {
  __shared__ float row[64][64];
  int t = threadIdx.x;
  int r = blockIdx.x*64 + t;          // r < O*32
  int o = r >> 5, kk = r & 31;
  float* my = row[t];
  if (kk == 20) {
    for (int i2 = 0; i2 < 64; ++i2) my[i2] = w[(size_t)o*64 + i2];
  } else if (kk < 20) {
    for (int i2 = 0; i2 < 64; ++i2) my[i2] = 0.f;
    for (int j = 0; j < 64; ++j) my[idx[j*KNN + kk]] += w[(size_t)o*64 + j];
  } else {
    for (int i2 = 0; i2 < 64; ++i2) my[i2] = 0.f;
  }
  for (int i2 = 0; i2 < 64; ++i2) {
    float v = my[i2];
    __hip_bfloat16 h = __float2bfloat16(v);
    Ah[(size_t)r*64 + i2] = h;
    Al[(size_t)r*64 + i2] = __float2bfloat16(v - (float)h);
  }
}

// ---- build padded-32 A in bf16 (stage 4, P=128) ----
__global__ __launch_bounds__(64) void k_build_A_bf(const float* w, const int* idx, __hip_bfloat16* A) {
  __shared__ float row[64][128];
  int t = threadIdx.x;
  int r = blockIdx.x*64 + t;          // r < 8192
  int o = r >> 5, kk = r & 31;
  float* my = row[t];
  if (kk == 20) {
    for (int i2 = 0; i2 < 128; ++i2) my[i2] = w[(size_t)o*128 + i2];
  } else if (kk < 20) {
    for (int i2 = 0; i2 < 128; ++i2) my[i2] = 0.f;
    for (int j = 0; j < 128; ++j) my[idx[j*KNN + kk]] += w[(size_t)o*128 + j];
  } else {
    for (int i2 = 0; i2 < 128; ++i2) my[i2] = 0.f;
  }
  for (int i2 = 0; i2 < 128; ++i2) A[(size_t)r*128 + i2] = __float2bfloat16(my[i2]);
}

// ---- f32 -> bf16 conversion (grid*256*16 elements) ----
__global__ __launch_bounds__(256) void k_f32_to_bf16(const float* in, __hip_bfloat16* out) {
  size_t base = ((size_t)blockIdx.x*256 + threadIdx.x) * 16;
  #pragma unroll
  for (int j = 0; j < 4; ++j) {
    float4 v = *(const float4*)(in + base + j*4);
    __hip_bfloat16 tmp[4] = {__float2bfloat16(v.x), __float2bfloat16(v.y),
                             __float2bfloat16(v.z), __float2bfloat16(v.w)};
    *(ushort4*)(out + base + j*4) = *(const ushort4*)tmp;
  }
}

// ---- f32 -> (hi, lo) bf16 split (grid*256*4 elements) ----
__global__ __launch_bounds__(256) void k_split_bf16x2(const float* in, __hip_bfloat16* hi, __hip_bfloat16* lo) {
  size_t base = ((size_t)blockIdx.x*256 + threadIdx.x) * 4;
  float4 v = *(const float4*)(in + base);
  float a[4] = {v.x, v.y, v.z, v.w};
  __hip_bfloat16 h[4], l[4];
  #pragma unroll
  for (int j = 0; j < 4; ++j) {
    h[j] = __float2bfloat16(a[j]);
    l[j] = __float2bfloat16(a[j] - (float)h[j]);
  }
  *(ushort4*)(hi + base) = *(const ushort4*)h;
  *(ushort4*)(lo + base) = *(const ushort4*)l;
}

// ---- stages 2/3 fused edge-conv, bf16x3-split MFMA (K=64); monotone-max epilogue ----
__global__ __launch_bounds__(512, 2) void k_fconv_mfma(const __hip_bfloat16* Ah, const __hip_bfloat16* Al,
                                                       const __hip_bfloat16* Bh, const __hip_bfloat16* Bl,
                                                       const float* sc, const float* sh,
                                                       int C, int nit, float* outx) {
  __shared__ char Bs[65536];           // hi [256 rows][128B] + lo at +32768, XOR-swizzled
  __shared__ float scl[16], shl[16];
  int t = threadIdx.x, bx = blockIdx.x, byg = blockIdx.y;
  int m0 = bx*256;
  for (int u = t; u < 256*8; u += 512) {
    int row = u >> 3, k8 = u & 7;
    s16x8 v = *(const s16x8*)(Bh + (size_t)(m0+row)*64 + k8*8);
    *(s16x8*)(Bs + row*128 + ((k8*16) ^ ((row&7)<<4))) = v;
  }
  for (int u = t; u < 256*8; u += 512) {
    int row = u >> 3, k8 = u & 7;
    s16x8 v = *(const s16x8*)(Bl + (size_t)(m0+row)*64 + k8*8);
    *(s16x8*)(Bs + 32768 + row*128 + ((k8*16) ^ ((row&7)<<4))) = v;
  }
  int obase = byg*4*nit;
  if (t < 4*nit) { scl[t] = sc[obase + t]; shl[t] = sh[obase + t]; }
  __syncthreads();
  int lane = t & 63, w = t >> 6;
  int col = lane & 15, lg = lane >> 4;
  int q = w & 3, pb = w >> 2;
  for (int it = 0; it < nit; ++it) {
    int by = byg*2*nit + it*2 + pb;    // o-pair index
    int rb = by*64;
    f32x4 acc[4][4] = {};
    #pragma unroll
    for (int ks = 0; ks < 2; ++ks) {
      int kel = ks*32 + lg*8;
      int kbyte = ks*64 + lg*16;
      s16x8 ah[4], al[4], bh[4], bl[4];
      #pragma unroll
      for (int at = 0; at < 4; ++at) {
        int r = rb + at*16 + col;
        ah[at] = *(const s16x8*)(Ah + (size_t)r*64 + kel);
        al[at] = *(const s16x8*)(Al + (size_t)r*64 + kel);
      }
      #pragma unroll
      for (int bt = 0; bt < 4; ++bt) {
        int r = q*64 + bt*16 + col;
        int off = r*128 + (kbyte ^ ((r & 7) << 4));
        bh[bt] = *(const s16x8*)(Bs + off);
        bl[bt] = *(const s16x8*)(Bs + 32768 + off);
      }
      #pragma unroll
      for (int at = 0; at < 4; ++at)
        #pragma unroll
        for (int bt = 0; bt < 4; ++bt) {
          acc[at][bt] = __builtin_amdgcn_mfma_f32_16x16x32_bf16(al[at], bh[bt], acc[at][bt], 0, 0, 0);
          acc[at][bt] = __builtin_amdgcn_mfma_f32_16x16x32_bf16(ah[at], bl[bt], acc[at][bt], 0, 0, 0);
          acc[at][bt] = __builtin_amdgcn_mfma_f32_16x16x32_bf16(ah[at], bh[bt], acc[at][bt], 0, 0, 0);
        }
    }
    int o0 = by*2;
    #pragma unroll
    for (int ol = 0; ol < 2; ++ol) {
      float scale = scl[o0 + ol - obase], shift = shl[o0 + ol - obase];
      float mxv[4], ctv[4];
      #pragma unroll
      for (int bt = 0; bt < 4; ++bt) {
        float h2b = __shfl(acc[2*ol+1][bt][0], 16 + col);
        float mxa = acc[2*ol][bt][0], mna = acc[2*ol][bt][0];
        #pragma unroll
        for (int qq = 1; qq < 4; ++qq) {
          mxa = fmaxf(mxa, acc[2*ol][bt][qq]);
          mna = fminf(mna, acc[2*ol][bt][qq]);
        }
        if (lg == 0) {
          #pragma unroll
          for (int qq = 0; qq < 4; ++qq) {
            mxa = fmaxf(mxa, acc[2*ol+1][bt][qq]);
            mna = fminf(mna, acc[2*ol+1][bt][qq]);
          }
        }
        mxa = fmaxf(mxa, __shfl_xor(mxa, 16));
        mna = fminf(mna, __shfl_xor(mna, 16));
        mxa = fmaxf(mxa, __shfl_xor(mxa, 32));
        mna = fminf(mna, __shfl_xor(mna, 32));
        float sel = (scale >= 0.f) ? mxa : mna;
        mxv[bt] = lrelu((sel - h2b)*scale + shift);
        ctv[bt] = lrelu(h2b*scale + shift);
      }
      float vb = (lg == 0) ? mxv[0] : (lg == 1) ? mxv[1] : (lg == 2) ? mxv[2] : mxv[3];
      float vc = (lg == 0) ? ctv[0] : (lg == 1) ? ctv[1] : (lg == 2) ? ctv[2] : ctv[3];
      size_t pbase = (size_t)(o0+ol)*2*C + m0 + q*64 + lane;
      outx[pbase] = vb;
      outx[pbase + C] = vc;
    }
  }
}

// ---- stage-4 edge-conv, bf16 MFMA: pipelined A-loads, sc/sh in LDS, monotone-max epilogue ----
__global__ __launch_bounds__(512, 2) void k_conv4_mfma(const __hip_bfloat16* Abf, const __hip_bfloat16* Xbf,
                                                       const float* sc, const float* sh, float* x4) {
  constexpr int MT = 256;
  __shared__ char Bs[MT*256];          // 64 KB, XOR-swizzled rows
  __shared__ float scl[32], shl[32];
  int t = threadIdx.x, bx = blockIdx.x, byg = blockIdx.y;
  int m0 = bx*MT;
  for (int u = t; u < MT*16; u += 512) {
    int row = u >> 4, k8 = u & 15;
    s16x8 v = *(const s16x8*)(Xbf + ((size_t)(m0+row) << 7) + (k8 << 3));
    *(s16x8*)(Bs + (row << 8) + ((k8 << 4) ^ ((row & 7) << 4))) = v;
  }
  if (t < 32) { scl[t] = sc[byg*32 + t]; shl[t] = sh[byg*32 + t]; }
  __syncthreads();
  int lane = t & 63, w = t >> 6;
  int col = lane & 15, lg = lane >> 4;
  int q = w & 3, pb = w >> 2;
  s16x8 a0[4];
  {
    const __hip_bfloat16* Ab = Abf + ((size_t)((byg*16 + pb)*64) << 7);
    #pragma unroll
    for (int at = 0; at < 4; ++at)
      a0[at] = *(const s16x8*)(Ab + ((size_t)(at*16 + col) << 7) + lg*8);
  }
  for (int it = 0; it < 8; ++it) {
    int by = byg*16 + it*2 + pb;
    const __hip_bfloat16* Ab = Abf + ((size_t)(by*64) << 7);
    f32x4 acc[4][4] = {};
    s16x8 a1[4];
    #pragma unroll
    for (int at = 0; at < 4; ++at)
      a1[at] = *(const s16x8*)(Ab + ((size_t)(at*16 + col) << 7) + 32 + lg*8);
    {
      int kbyte = lg*16;
      s16x8 b[4];
      #pragma unroll
      for (int bt = 0; bt < 4; ++bt) {
        int r = q*64 + bt*16 + col;
        b[bt] = *(const s16x8*)(Bs + (r << 8) + (kbyte ^ ((r & 7) << 4)));
      }
      __builtin_amdgcn_s_setprio(1);
      #pragma unroll
      for (int at = 0; at < 4; ++at)
        #pragma unroll
        for (int bt = 0; bt < 4; ++bt)
          acc[at][bt] = __builtin_amdgcn_mfma_f32_16x16x32_bf16(a0[at], b[bt], acc[at][bt], 0, 0, 0);
      __builtin_amdgcn_s_setprio(0);
    }
    s16x8 a2[4];
    #pragma unroll
    for (int at = 0; at < 4; ++at)
      a2[at] = *(const s16x8*)(Ab + ((size_t)(at*16 + col) << 7) + 64 + lg*8);
    {
      int kbyte = 64 + lg*16;
      s16x8 b[4];
      #pragma unroll
      for (int bt = 0; bt < 4; ++bt) {
        int r = q*64 + bt*16 + col;
        b[bt] = *(const s16x8*)(Bs + (r << 8) + (kbyte ^ ((r & 7) << 4)));
      }
      __builtin_amdgcn_s_setprio(1);
      #pragma unroll
      for (int at = 0; at < 4; ++at)
        #pragma unroll
        for (int bt = 0; bt < 4; ++bt)
          acc[at][bt] = __builtin_amdgcn_mfma_f32_16x16x32_bf16(a1[at], b[bt], acc[at][bt], 0, 0, 0);
      __builtin_amdgcn_s_setprio(0);
    }
    s16x8 a3[4], a0n[4];
    #pragma unroll
    for (int at = 0; at < 4; ++at)
      a3[at] = *(const s16x8*)(Ab + ((size_t)(at*16 + col) << 7) + 96 + lg*8);
    {
      int byN = (it < 7) ? (by + 2) : by;
      const __hip_bfloat16* AbN = Abf + ((size_t)(byN*64) << 7);
      #pragma unroll
      for (int at = 0; at < 4; ++at)
        a0n[at] = *(const s16x8*)(AbN + ((size_t)(at*16 + col) << 7) + lg*8);
    }
    {
      int kbyte = 128 + lg*16;
      s16x8 b[4];
      #pragma unroll
      for (int bt = 0; bt < 4; ++bt) {
        int r = q*64 + bt*16 + col;
        b[bt] = *(const s16x8*)(Bs + (r << 8) + (kbyte ^ ((r & 7) << 4)));
      }
      __builtin_amdgcn_s_setprio(1);
      #pragma unroll
      for (int at = 0; at < 4; ++at)
        #pragma unroll
        for (int bt = 0; bt < 4; ++bt)
          acc[at][bt] = __builtin_amdgcn_mfma_f32_16x16x32_bf16(a2[at], b[bt], acc[at][bt], 0, 0, 0);
      __builtin_amdgcn_s_setprio(0);
    }
    {
      int kbyte = 192 + lg*16;
      s16x8 b[4];
      #pragma unroll
      for (int bt = 0; bt < 4; ++bt) {
        int r = q*64 + bt*16 + col;
        b[bt] = *(const s16x8*)(Bs + (r << 8) + (kbyte ^ ((r & 7) << 4)));
      }
      __builtin_amdgcn_s_setprio(1);
      #pragma unroll
      for (int at = 0; at < 4; ++at)
        #pragma unroll
        for (int bt = 0; bt < 4; ++bt)
          acc[at][bt] = __builtin_amdgcn_mfma_f32_16x16x32_bf16(a3[at], b[bt], acc[at][bt], 0, 0, 0);
      __builtin_amdgcn_s_setprio(0);
    }
    // monotone-max epilogue
    int o0 = by*2;
    int sbase = it*4 + pb*2;
    #pragma unroll
    for (int ol = 0; ol < 2; ++ol) {
      float scale = scl[sbase + ol], shift = shl[sbase + ol];
      float mxv[4], ctv[4];
      #pragma unroll
      for (int bt = 0; bt < 4; ++bt) {
        float h2b = __shfl(acc[2*ol+1][bt][0], 16 + col);
        float mxa = acc[2*ol][bt][0], mna = acc[2*ol][bt][0];
        #pragma unroll
        for (int qq = 1; qq < 4; ++qq) {
          mxa = fmaxf(mxa, acc[2*ol][bt][qq]);
          mna = fminf(mna, acc[2*ol][bt][qq]);
        }
        if (lg == 0) {
          #pragma unroll
          for (int qq = 0; qq < 4; ++qq) {
            mxa = fmaxf(mxa, acc[2*ol+1][bt][qq]);
            mna = fminf(mna, acc[2*ol+1][bt][qq]);
          }
        }
        mxa = fmaxf(mxa, __shfl_xor(mxa, 16));
        mna = fminf(mna, __shfl_xor(mna, 16));
        mxa = fmaxf(mxa, __shfl_xor(mxa, 32));
        mna = fminf(mna, __shfl_xor(mna, 32));
        float sel = (scale >= 0.f) ? mxa : mna;
        mxv[bt] = lrelu((sel - h2b)*scale + shift);
        ctv[bt] = lrelu(h2b*scale + shift);
      }
      float vb = (lg == 0) ? mxv[0] : (lg == 1) ? mxv[1] : (lg == 2) ? mxv[2] : mxv[3];
      float vc = (lg == 0) ? ctv[0] : (lg == 1) ? ctv[1] : (lg == 2) ? ctv[2] : ctv[3];
      size_t pbase = (size_t)(o0+ol)*32768 + m0 + q*64 + lane;
      x4[pbase] = vb;
      x4[pbase + 16384] = vc;
    }
    #pragma unroll
    for (int at = 0; at < 4; ++at) a0[at] = a0n[at];
  }
}

// ---- stage 5 via bf16 MFMA ----
__global__ __launch_bounds__(256) void k_s5_mfma(const float* x4, const __hip_bfloat16* w5bf,
                                                 const float* sc, const float* sh,
                                                 float* pm, float* ps) {
  __shared__ char smem[8192 + 32768];
  __shared__ float redm[64][4];
  __shared__ float reds[64][4];
  int t = threadIdx.x, bx = blockIdx.x, by = blockIdx.y;
  int p0 = bx*256, o0 = by*64;
  int lane = t & 63, w = t >> 6;
  int lrow = lane & 15, lg = lane >> 4;
  char* As = smem;
  char* Bs = smem + 8192;
  f32x4 acc[4][4] = {};
  for (int c0 = 0; c0 < 256; c0 += 64) {
    for (int u = t; u < 64*8; u += 256) {
      int row = u >> 3, k8 = u & 7;
      s16x8 v = *(const s16x8*)(w5bf + (size_t)(o0+row)*256 + c0 + k8*8);
      *(s16x8*)(As + row*128 + ((k8*16) ^ ((row&7)<<4))) = v;
    }
    #pragma unroll
    for (int i = 0; i < 8; ++i) {
      __hip_bfloat16 tmp[8];
      #pragma unroll
      for (int j = 0; j < 8; ++j)
        tmp[j] = __float2bfloat16(x4[(size_t)(c0 + i*8 + j)*32768 + p0 + t]);
      *(s16x8*)(Bs + t*128 + ((i*16) ^ ((t&7)<<4))) = *(const s16x8*)tmp;
    }
    __syncthreads();
    #pragma unroll
    for (int ksub = 0; ksub < 2; ++ksub) {
      int kbyte = ksub*64 + lg*16;
      s16x8 a[4], b[4];
      #pragma unroll
      for (int rt = 0; rt < 4; ++rt) { int r = rt*16 + lrow; a[rt] = *(const s16x8*)(As + r*128 + (kbyte ^ ((r&7)<<4))); }
      #pragma unroll
      for (int cf = 0; cf < 4; ++cf) { int r = w*64 + cf*16 + lrow; b[cf] = *(const s16x8*)(Bs + r*128 + (kbyte ^ ((r&7)<<4))); }
      #pragma unroll
      for (int rt = 0; rt < 4; ++rt)
        #pragma unroll
        for (int cf = 0; cf < 4; ++cf)
          acc[rt][cf] = __builtin_amdgcn_mfma_f32_16x16x32_bf16(a[rt], b[cf], acc[rt][cf], 0, 0, 0);
    }
    __syncthreads();
  }
  #pragma unroll
  for (int rt = 0; rt < 4; ++rt) {
    #pragma unroll
    for (int q = 0; q < 4; ++q) {
      int ol = rt*16 + lg*4 + q;
      float scale = sc[o0+ol], shift = sh[o0+ol];
      float mx = -FLT_MAX, sm = 0.f;
      #pragma unroll
      for (int cf = 0; cf < 4; ++cf) {
        float h = lrelu(acc[rt][cf][q]*scale + shift);
        mx = fmaxf(mx, h); sm += h;
      }
      #pragma unroll
      for (int off2 = 1; off2 < 16; off2 <<= 1) {
        mx = fmaxf(mx, __shfl_xor(mx, off2));
        sm += __shfl_xor(sm, off2);
      }
      if (lrow == 0) { redm[ol][w] = mx; reds[ol][w] = sm; }
    }
  }
  __syncthreads();
  if (t < 64) {
    float mx = fmaxf(fmaxf(redm[t][0], redm[t][1]), fmaxf(redm[t][2], redm[t][3]));
    float sm = reds[t][0] + reds[t][1] + reds[t][2] + reds[t][3];
    pm[(size_t)(o0 + t)*128 + bx] = mx;
    ps[(size_t)(o0 + t)*128 + bx] = sm;
  }
}

__global__ __launch_bounds__(512) void k_pool(const float* pm, const float* ps, float* z0) {
  int t = threadIdx.x;
  for (int o = t; o < 512; o += 512) {
    float mx = -FLT_MAX, sm = 0.f;
    for (int nt = 0; nt < 128; ++nt) { mx = fmaxf(mx, pm[(size_t)o*128+nt]); sm += ps[(size_t)o*128+nt]; }
    z0[o] = mx;
    z0[512+o] = sm * (1.f/32768.f);
  }
}

__global__ __launch_bounds__(128) void k_fc1(const float* z0, const float* lw1, float* z1) {
  int bx = blockIdx.x, t = threadIdx.x;
  int rl = t >> 4, cl = t & 15;
  int r = bx*8 + rl;
  float acc = 0.f;
  for (int u = 0; u < 64; ++u) {
    int c = cl*64 + u;
    acc += z0[c] * lw1[(size_t)r*1024 + c];
  }
  #pragma unroll
  for (int off = 1; off < 16; off <<= 1) acc += __shfl_xor(acc, off);
  if (cl == 0) z1[r] = lrelu(acc);
}

__global__ __launch_bounds__(128) void k_fc2(const float* z1, const float* lw2,
                                             const float* lb2, float* z2) {
  int bx = blockIdx.x, t = threadIdx.x;
  int rl = t >> 4, cl = t & 15;
  int r = bx*8 + rl;
  float acc = 0.f;
  for (int u = 0; u < 32; ++u) {
    int c = cl*32 + u;
    acc += z1[c] * lw2[(size_t)r*512 + c];
  }
  #pragma unroll
  for (int off = 1; off < 16; off <<= 1) acc += __shfl_xor(acc, off);
  if (cl == 0) z2[r] = lrelu(acc + lb2[r]);
}

__global__ __launch_bounds__(64) void k_fc3(const float* z2, const float* ow,
                                            const float* ob, float* out) {
  __shared__ float lg[11];
  __shared__ float ex[11];
  int t = threadIdx.x;
  if (t < 11) {
    float acc = 0.f;
    for (int c = 0; c < 256; ++c) acc += z2[c] * ow[t*256 + c];
    lg[t] = acc + ob[t];
  }
  __syncthreads();
  if (t < 11) {
    float m = -FLT_MAX;
    for (int r = 0; r < 11; ++r) m = fmaxf(m, lg[r]);
    ex[t] = expf(lg[t] - m);
  }
  __syncthreads();
  if (t < 11) {
    float s = 0.f;
    for (int r = 0; r < 11; ++r) s += ex[r];
    out[t] = ex[t] / s;
  }
}

extern "C" void kernel_launch(void* const* d_in, const int* in_sizes, int n_in,
                              void* d_out, int out_size, void* d_ws, size_t ws_size,
                              hipStream_t stream) {
  auto f = [&](int i) { return (const float*)d_in[i]; };
  float* ws = (float*)d_ws;
  int* idx = (int*)(ws + OFF_IDX);
  float* out = (float*)d_out;

  if (ws_size < WS_NEEDED_BYTES) {
    k_ws_sentinel<<<1, 64, 0, stream>>>(out, (float)(ws_size >> 20));
    return;
  }

  __hip_bfloat16* Abf = (__hip_bfloat16*)(ws + OFF_ABF);
  __hip_bfloat16* Xbf = (__hip_bfloat16*)(ws + OFF_GP);       // after dist4 consumed partials
  __hip_bfloat16* w5bf = (__hip_bfloat16*)(ws + OFF_W5BF);
  float* x4 = ws + OFF_X4;
  __hip_bfloat16* Xh = (__hip_bfloat16*)(ws + OFF_SPLIT);
  __hip_bfloat16* X1L = Xh + 262144;                          // stage-2: x1 hi/lo (64*4096 each)
  __hip_bfloat16* X2L = Xh + 524288;                          // stage-3: x2 hi/lo (64*8192 each)
  __hip_bfloat16* A2H = (__hip_bfloat16*)(ws + OFF_A);
  __hip_bfloat16* A2L = A2H + 131072;                         // 2048*64 each
  __hip_bfloat16* A3H = (__hip_bfloat16*)(ws + OFF_A);
  __hip_bfloat16* A3L = A3H + 262144;                         // 4096*64 each

  k_bn_pre<<<1, 512, 0, stream>>>(f(2),f(3),f(4),f(5), f(7),f(8),f(9),f(10),
                                  f(12),f(13),f(14),f(15), f(17),f(18),f(19),f(20),
                                  f(22),f(23),f(24),f(25), ws);
  // stage 1 (4 waves/block register top-k; hierarchical group maxima)
  k_s1_topk<<<N/4, 256, 0, stream>>>(f(0), idx);
  k_s1_conv<<<dim3(N/64, 16), 256, 0, stream>>>(f(0), f(1), idx, ws+OFF_SC1, ws+OFF_SH1, ws+OFF_X1);
  // stage 2: prev=x1 (M=4096,P=64,O=64) — kNN f32, conv bf16x3 MFMA
  k_gram_partial<64><<<64, 256, 0, stream>>>(ws+OFF_X1, 4096, ws+OFF_GP);
  k_dist_topk<64><<<64, 256, 0, stream>>>(ws+OFF_GP, idx, 64);
  k_build_A_bf32<<<32, 64, 0, stream>>>(f(6), idx, A2H, A2L);
  k_split_bf16x2<<<256, 256, 0, stream>>>(ws+OFF_X1, Xh, X1L);
  k_fconv_mfma<<<dim3(16, 8), 512, 0, stream>>>(A2H, A2L, Xh, X1L, ws+OFF_SC2, ws+OFF_SH2, 4096, 2, ws+OFF_X2);
  // stage 3: prev=x2 (M=8192,P=64,O=128)
  k_gram_partial<64><<<64, 256, 0, stream>>>(ws+OFF_X2, 8192, ws+OFF_GP);
  k_dist_topk<64><<<64, 256, 0, stream>>>(ws+OFF_GP, idx, 64);
  k_build_A_bf32<<<64, 64, 0, stream>>>(f(11), idx, A3H, A3L);
  k_split_bf16x2<<<512, 256, 0, stream>>>(ws+OFF_X2, Xh, X2L);
  k_fconv_mfma<<<dim3(32, 8), 512, 0, stream>>>(A3H, A3L, Xh, X2L, ws+OFF_SC3, ws+OFF_SH3, 8192, 4, ws+OFF_X3);
  // stage 4: prev=x3 (M=16384,P=128,O=256) — kNN f32, conv bf16 MFMA
  k_gram_partial<128><<<64, 256, 0, stream>>>(ws+OFF_X3, 16384, ws+OFF_GP);
  k_dist_topk<128><<<128, 256, 0, stream>>>(ws+OFF_GP, idx, 64);
  k_build_A_bf<<<128, 64, 0, stream>>>(f(16), idx, Abf);
  k_f32_to_bf16<<<512, 256, 0, stream>>>(ws+OFF_X3, Xbf);
  k_conv4_mfma<<<dim3(16384/256, 8), 512, 0, stream>>>(Abf, Xbf, ws+OFF_SC4, ws+OFF_SH4, x4);
  // stage 5 (bf16 MFMA, pooling fused) + head
  k_f32_to_bf16<<<32, 256, 0, stream>>>(f(21), w5bf);
  k_s5_mfma<<<dim3(128, 8), 256, 0, stream>>>(x4, w5bf, ws+OFF_SC5, ws+OFF_SH5, ws+OFF_PM, ws+OFF_PS);
  k_pool<<<1, 512, 0, stream>>>(ws+OFF_PM, ws+OFF_PS, ws+OFF_Z0);
  k_fc1<<<64, 128, 0, stream>>>(ws+OFF_Z0, f(26), ws+OFF_Z1);
  k_fc2<<<32, 128, 0, stream>>>(ws+OFF_Z1, f(27), f(28), ws+OFF_Z2);
  k_fc3<<<1, 64, 0, stream>>>(ws+OFF_Z2, f(29), f(30), out);
}

// Round 18
// 428.875 us; speedup vs baseline: 1.0548x; 1.0548x over previous
//
#include <hip/hip_runtime.h>
#include <hip/hip_bf16.h>
#include <float.h>
#include <math.h>

#define DEV __device__ __forceinline__

DEV float lrelu(float x) { return x >= 0.f ? x : 0.2f * x; }

constexpr int N = 4096, KNN = 20;

typedef __attribute__((ext_vector_type(4))) float f32x4;
typedef __attribute__((ext_vector_type(8))) short s16x8;

// ---- ws layout (float offsets) ----
constexpr size_t OFF_SC1 = 0,    OFF_SH1 = 64;
constexpr size_t OFF_SC2 = 128,  OFF_SH2 = 192;
constexpr size_t OFF_SC3 = 256,  OFF_SH3 = 384;
constexpr size_t OFF_SC4 = 512,  OFF_SH4 = 768;
constexpr size_t OFF_SC5 = 1024, OFF_SH5 = 1536;
constexpr size_t OFF_X1 = 2048;                              // 64*4096
constexpr size_t OFF_X2 = OFF_X1 + (size_t)64*4096;          // 64*8192
constexpr size_t OFF_X3 = OFF_X2 + (size_t)64*8192;          // 128*16384
constexpr size_t OFF_X4 = OFF_X3 + (size_t)128*16384;        // x4 f32 [512 logical o][16384 p]
constexpr size_t OFF_A  = OFF_X4 + (size_t)256*32768;        // A splits (s2/s3), stage4 Abf + w5bf
constexpr size_t OFF_GP = OFF_A + (size_t)256*21*128;        // 4MB: gram partials [0,1MB); hi/lo splits [2MB,4MB); x3-bf16 later
constexpr size_t OFF_PM = OFF_GP + (size_t)64*128*128;       // 512*128
constexpr size_t OFF_PS = OFF_PM + (size_t)512*256;          // 512*128
constexpr size_t OFF_Z0 = OFF_PS + (size_t)512*256;          // 1024
constexpr size_t OFF_Z1 = OFF_Z0 + 1024;                     // 512
constexpr size_t OFF_Z2 = OFF_Z1 + 512;                      // 256
constexpr size_t OFF_IDX = OFF_Z2 + 256;                     // ints, 4096*20
constexpr size_t WS_NEEDED_BYTES = OFF_IDX * 4 + (size_t)N * KNN * 4;
constexpr size_t OFF_ABF = OFF_A;                            // stage-4 padded A, bf16: 8192*128
constexpr size_t OFF_W5BF = OFF_A + 524288;                  // bf16 w5 (512*256) after Abf
constexpr size_t OFF_SPLIT = OFF_GP + 524288;                // hi/lo split area (bytes [2MB,4MB) of GP)

// ---- ws-too-small sentinel ----
__global__ void k_ws_sentinel(float* out, float mb) {
  int t = threadIdx.x;
  if (t < 11) out[t] = 1.0e6f + mb;
}

// ---- bn scale/shift precompute ----
__global__ __launch_bounds__(512) void k_bn_pre(
    const float* g1, const float* b1, const float* m1, const float* v1,
    const float* g2, const float* b2, const float* m2, const float* v2,
    const float* g3, const float* b3, const float* m3, const float* v3,
    const float* g4, const float* b4, const float* m4, const float* v4,
    const float* g5, const float* b5, const float* m5, const float* v5,
    float* ws) {
  int t = threadIdx.x;
  const float* G[5] = {g1,g2,g3,g4,g5};
  const float* B[5] = {b1,b2,b3,b4,b5};
  const float* M[5] = {m1,m2,m3,m4,m5};
  const float* V[5] = {v1,v2,v3,v4,v5};
  const size_t SC[5] = {OFF_SC1,OFF_SC2,OFF_SC3,OFF_SC4,OFF_SC5};
  const size_t SH[5] = {OFF_SH1,OFF_SH2,OFF_SH3,OFF_SH4,OFF_SH5};
  const int CN[5] = {64,64,128,256,512};
  for (int s = 0; s < 5; ++s) {
    for (int i = t; i < CN[s]; i += 512) {
      float scale = G[s][i] / sqrtf(V[s][i] + 1e-5f);
      ws[SC[s] + i] = scale;
      ws[SH[s] + i] = B[s][i] - M[s][i] * scale;
    }
  }
}

// ---- stage 1 top-20 v4: 4 waves/block, hierarchical 8x8 group maxima ----
__global__ __launch_bounds__(256) void k_s1_topk(const float* x, int* idx) {
  int t = threadIdx.x;
  int lane = t & 63, wid = t >> 6;
  int i = blockIdx.x*4 + wid;
  float v[64];
  {
    #pragma clang fp contract(off)
    float xi0 = x[i], xi1 = x[N + i], xi2 = x[2*N + i];
    float sqi = xi0*xi0 + xi1*xi1 + xi2*xi2;
    #pragma unroll
    for (int u = 0; u < 64; ++u) {
      int j = u*64 + lane;
      float xj0 = x[j], xj1 = x[N+j], xj2 = x[2*N+j];
      float sqj = xj0*xj0 + xj1*xj1 + xj2*xj2;
      float p = xi0*xj0 + xi1*xj1 + xi2*xj2;
      v[u] = (2.f*p - sqi) - sqj;
    }
  }
  float gv[8]; int gu[8];
  #pragma unroll
  for (int g = 0; g < 8; ++g) {
    float m = v[g*8]; int mu = g*8;
    #pragma unroll
    for (int u2 = 1; u2 < 8; ++u2)
      if (v[g*8+u2] > m) { m = v[g*8+u2]; mu = g*8+u2; }
    gv[g] = m; gu[g] = mu;
  }
  float bv; int bu;
  bv = gv[0]; bu = gu[0];
  #pragma unroll
  for (int g = 1; g < 8; ++g) if (gv[g] > bv) { bv = gv[g]; bu = gu[g]; }
  int bi = bu*64 + lane;
  for (int k = 0; k < KNN; ++k) {
    float rv = bv; int ri = bi;
    #pragma unroll
    for (int off = 1; off < 64; off <<= 1) {
      float v2 = __shfl_xor(rv, off); int i2 = __shfl_xor(ri, off);
      if (v2 > rv || (v2 == rv && i2 < ri)) { rv = v2; ri = i2; }
    }
    if (lane == 0) idx[i*KNN + k] = ri;
    if ((ri & 63) == lane) {
      int wu = ri >> 6;
      int wg = wu >> 3;
      #pragma unroll
      for (int g = 0; g < 8; ++g) {
        if (g == wg) {
          float m = -FLT_MAX; int mu = g*8;
          #pragma unroll
          for (int u2 = 0; u2 < 8; ++u2) {
            if (g*8+u2 == wu) v[g*8+u2] = -FLT_MAX;
            float val = v[g*8+u2];
            if (val > m) { m = val; mu = g*8+u2; }
          }
          gv[g] = m; gu[g] = mu;
        }
      }
      bv = gv[0]; bu = gu[0];
      #pragma unroll
      for (int g = 1; g < 8; ++g) if (gv[g] > bv) { bv = gv[g]; bu = gu[g]; }
      bi = bu*64 + lane;
    }
  }
}

// ---- stage 1 conv ----
__global__ __launch_bounds__(256) void k_s1_conv(const float* x, const float* w1g,
                                                 const int* idx, const float* sc, const float* sh, float* x1) {
  __shared__ int idxs[64][KNN];
  __shared__ float xs[3][64];
  __shared__ float wsh[4][6];
  int t = threadIdx.x, bx = blockIdx.x, by = blockIdx.y;
  int i0 = bx * 64;
  for (int u = t; u < 64*KNN; u += 256) idxs[u/KNN][u%KNN] = idx[(size_t)(i0 + u/KNN)*KNN + u%KNN];
  for (int u = t; u < 3*64; u += 256) xs[u/64][u%64] = x[(size_t)(u/64)*N + i0 + (u%64)];
  for (int u = t; u < 24; u += 256) wsh[u/6][u%6] = w1g[(size_t)(by*4 + u/6)*6 + u%6];
  __syncthreads();
  int il = t & 63, ol = t >> 6;
  int o = by*4 + ol, i = i0 + il;
  float xi0 = xs[0][il], xi1 = xs[1][il], xi2 = xs[2][il];
  float w0 = wsh[ol][0], w1v = wsh[ol][1], w2v = wsh[ol][2];
  float w3v = wsh[ol][3], w4v = wsh[ol][4], w5v = wsh[ol][5];
  float ctr = w3v*xi0 + w4v*xi1 + w5v*xi2;
  float scale = sc[o], shift = sh[o];
  float best = -FLT_MAX;
  for (int k = 0; k < KNN; ++k) {
    int j = idxs[il][k];
    float h = w0*(x[j] - xi0) + w1v*(x[N+j] - xi1) + w2v*(x[2*N+j] - xi2) + ctr;
    h = lrelu(h*scale + shift);
    best = fmaxf(best, h);
  }
  x1[(size_t)o*N + i] = best;
}

// ---- partial Gram ----
template<int P>
__global__ __launch_bounds__(256) void k_gram_partial(const float* prev, int C, float* gp) {
  constexpr int BI = P / 16;
  __shared__ float ysh[32][P];
  int b = blockIdx.x, t = threadIdx.x;
  int R = C / gridDim.x;
  int base = b * R;
  float acc[BI][BI] = {};
  int i0 = (t >> 4) * BI, j0 = (t & 15) * BI;
  for (int r0 = 0; r0 < R; r0 += 32) {
    for (int u = t; u < 32*P; u += 256) ysh[u/P][u%P] = prev[(size_t)(base + r0 + u/P)*P + (u%P)];
    __syncthreads();
    for (int r = 0; r < 32; ++r) {
      float yi[BI], yj[BI];
      #pragma unroll
      for (int a = 0; a < BI; ++a) { yi[a] = ysh[r][i0+a]; yj[a] = ysh[r][j0+a]; }
      #pragma unroll
      for (int a = 0; a < BI; ++a)
        #pragma unroll
        for (int c = 0; c < BI; ++c) acc[a][c] += yi[a]*yj[c];
    }
    __syncthreads();
  }
  for (int a = 0; a < BI; ++a)
    for (int c = 0; c < BI; ++c)
      gp[(size_t)b*P*P + (size_t)(i0+a)*P + (j0+c)] = acc[a][c];
}

// ---- reduce nb Gram partials + top-20; ILP-4 reduction (round-16 config) ----
template<int P>
__global__ __launch_bounds__(128) void k_dist_topk(const float* gp, int* idx, int nb) {
  __shared__ float dsh[P];
  __shared__ float diag[P];
  __shared__ float vsh[128];
  __shared__ int ish[128];
  int i = blockIdx.x, t = threadIdx.x;
  if (t < P) {
    int q = nb >> 2;
    float g0 = 0.f, g1 = 0.f, g2 = 0.f, g3 = 0.f;
    float e0 = 0.f, e1 = 0.f, e2 = 0.f, e3 = 0.f;
    for (int b = 0; b < q; ++b) {
      size_t o0 = (size_t)b*P*P, o1 = (size_t)(b+q)*P*P, o2 = (size_t)(b+2*q)*P*P, o3 = (size_t)(b+3*q)*P*P;
      g0 += gp[o0 + (size_t)i*P + t]; g1 += gp[o1 + (size_t)i*P + t];
      g2 += gp[o2 + (size_t)i*P + t]; g3 += gp[o3 + (size_t)i*P + t];
      e0 += gp[o0 + (size_t)t*P + t]; e1 += gp[o1 + (size_t)t*P + t];
      e2 += gp[o2 + (size_t)t*P + t]; e3 += gp[o3 + (size_t)t*P + t];
    }
    diag[t] = (e0 + e1) + (e2 + e3);
    dsh[t] = (g0 + g1) + (g2 + g3);
  }
  __syncthreads();
  if (t < P) dsh[t] = (2.f*dsh[t] - diag[i]) - diag[t];
  __syncthreads();
  for (int k = 0; k < KNN; ++k) {
    float bv = -FLT_MAX; int bi = P;
    if (t < P) { bv = dsh[t]; bi = t; }
    vsh[t] = bv; ish[t] = bi;
    __syncthreads();
    for (int s = 64; s > 0; s >>= 1) {
      if (t < s) {
        float v2 = vsh[t+s]; int i2 = ish[t+s];
        if (v2 > vsh[t] || (v2 == vsh[t] && i2 < ish[t])) { vsh[t] = v2; ish[t] = i2; }
      }
      __syncthreads();
    }
    if (t == 0) { idx[i*KNN + k] = ish[0]; dsh[ish[0]] = -FLT_MAX; }
    __syncthreads();
  }
}

// ---- build padded-32 A hi/lo bf16 (stages 2/3, P=64): row r = o*32+kk ----
__global__ __launch_bounds__(64) void k_build_A_bf32(const float* w, const int* idx,
                                                     __hip_bfloat16* Ah, __hip_bfloat16* Al) {
  __shared__ float row[64][64];
  int t = threadIdx.x;
  int r = blockIdx.x*64 + t;          // r < O*32
  int o = r >> 5, kk = r & 31;
  float* my = row[t];
  if (kk == 20) {
    for (int i2 = 0; i2 < 64; ++i2) my[i2] = w[(size_t)o*64 + i2];
  } else if (kk < 20) {
    for (int i2 = 0; i2 < 64; ++i2) my[i2] = 0.f;
    for (int j = 0; j < 64; ++j) my[idx[j*KNN + kk]] += w[(size_t)o*64 + j];
  } else {
    for (int i2 = 0; i2 < 64; ++i2) my[i2] = 0.f;
  }
  for (int i2 = 0; i2 < 64; ++i2) {
    float v = my[i2];
    __hip_bfloat16 h = __float2bfloat16(v);
    Ah[(size_t)r*64 + i2] = h;
    Al[(size_t)r*64 + i2] = __float2bfloat16(v - (float)h);
  }
}

// ---- build padded-32 A in bf16 (stage 4, P=128) ----
__global__ __launch_bounds__(64) void k_build_A_bf(const float* w, const int* idx, __hip_bfloat16* A) {
  __shared__ float row[64][128];
  int t = threadIdx.x;
  int r = blockIdx.x*64 + t;          // r < 8192
  int o = r >> 5, kk = r & 31;
  float* my = row[t];
  if (kk == 20) {
    for (int i2 = 0; i2 < 128; ++i2) my[i2] = w[(size_t)o*128 + i2];
  } else if (kk < 20) {
    for (int i2 = 0; i2 < 128; ++i2) my[i2] = 0.f;
    for (int j = 0; j < 128; ++j) my[idx[j*KNN + kk]] += w[(size_t)o*128 + j];
  } else {
    for (int i2 = 0; i2 < 128; ++i2) my[i2] = 0.f;
  }
  for (int i2 = 0; i2 < 128; ++i2) A[(size_t)r*128 + i2] = __float2bfloat16(my[i2]);
}

// ---- f32 -> bf16 conversion (grid*256*16 elements) ----
__global__ __launch_bounds__(256) void k_f32_to_bf16(const float* in, __hip_bfloat16* out) {
  size_t base = ((size_t)blockIdx.x*256 + threadIdx.x) * 16;
  #pragma unroll
  for (int j = 0; j < 4; ++j) {
    float4 v = *(const float4*)(in + base + j*4);
    __hip_bfloat16 tmp[4] = {__float2bfloat16(v.x), __float2bfloat16(v.y),
                             __float2bfloat16(v.z), __float2bfloat16(v.w)};
    *(ushort4*)(out + base + j*4) = *(const ushort4*)tmp;
  }
}

// ---- f32 -> (hi, lo) bf16 split (grid*256*4 elements) ----
__global__ __launch_bounds__(256) void k_split_bf16x2(const float* in, __hip_bfloat16* hi, __hip_bfloat16* lo) {
  size_t base = ((size_t)blockIdx.x*256 + threadIdx.x) * 4;
  float4 v = *(const float4*)(in + base);
  float a[4] = {v.x, v.y, v.z, v.w};
  __hip_bfloat16 h[4], l[4];
  #pragma unroll
  for (int j = 0; j < 4; ++j) {
    h[j] = __float2bfloat16(a[j]);
    l[j] = __float2bfloat16(a[j] - (float)h[j]);
  }
  *(ushort4*)(hi + base) = *(const ushort4*)h;
  *(ushort4*)(lo + base) = *(const ushort4*)l;
}

// ---- stages 2/3 fused edge-conv, bf16x3-split MFMA (K=64); monotone-max epilogue ----
__global__ __launch_bounds__(512, 2) void k_fconv_mfma(const __hip_bfloat16* Ah, const __hip_bfloat16* Al,
                                                       const __hip_bfloat16* Bh, const __hip_bfloat16* Bl,
                                                       const float* sc, const float* sh,
                                                       int C, int nit, float* outx) {
  __shared__ char Bs[65536];           // hi [256 rows][128B] + lo at +32768, XOR-swizzled
  __shared__ float scl[16], shl[16];
  int t = threadIdx.x, bx = blockIdx.x, byg = blockIdx.y;
  int m0 = bx*256;
  for (int u = t; u < 256*8; u += 512) {
    int row = u >> 3, k8 = u & 7;
    s16x8 v = *(const s16x8*)(Bh + (size_t)(m0+row)*64 + k8*8);
    *(s16x8*)(Bs + row*128 + ((k8*16) ^ ((row&7)<<4))) = v;
  }
  for (int u = t; u < 256*8; u += 512) {
    int row = u >> 3, k8 = u & 7;
    s16x8 v = *(const s16x8*)(Bl + (size_t)(m0+row)*64 + k8*8);
    *(s16x8*)(Bs + 32768 + row*128 + ((k8*16) ^ ((row&7)<<4))) = v;
  }
  int obase = byg*4*nit;
  if (t < 4*nit) { scl[t] = sc[obase + t]; shl[t] = sh[obase + t]; }
  __syncthreads();
  int lane = t & 63, w = t >> 6;
  int col = lane & 15, lg = lane >> 4;
  int q = w & 3, pb = w >> 2;
  for (int it = 0; it < nit; ++it) {
    int by = byg*2*nit + it*2 + pb;    // o-pair index
    int rb = by*64;
    f32x4 acc[4][4] = {};
    #pragma unroll
    for (int ks = 0; ks < 2; ++ks) {
      int kel = ks*32 + lg*8;
      int kbyte = ks*64 + lg*16;
      s16x8 ah[4], al[4], bh[4], bl[4];
      #pragma unroll
      for (int at = 0; at < 4; ++at) {
        int r = rb + at*16 + col;
        ah[at] = *(const s16x8*)(Ah + (size_t)r*64 + kel);
        al[at] = *(const s16x8*)(Al + (size_t)r*64 + kel);
      }
      #pragma unroll
      for (int bt = 0; bt < 4; ++bt) {
        int r = q*64 + bt*16 + col;
        int off = r*128 + (kbyte ^ ((r & 7) << 4));
        bh[bt] = *(const s16x8*)(Bs + off);
        bl[bt] = *(const s16x8*)(Bs + 32768 + off);
      }
      #pragma unroll
      for (int at = 0; at < 4; ++at)
        #pragma unroll
        for (int bt = 0; bt < 4; ++bt) {
          acc[at][bt] = __builtin_amdgcn_mfma_f32_16x16x32_bf16(al[at], bh[bt], acc[at][bt], 0, 0, 0);
          acc[at][bt] = __builtin_amdgcn_mfma_f32_16x16x32_bf16(ah[at], bl[bt], acc[at][bt], 0, 0, 0);
          acc[at][bt] = __builtin_amdgcn_mfma_f32_16x16x32_bf16(ah[at], bh[bt], acc[at][bt], 0, 0, 0);
        }
    }
    int o0 = by*2;
    #pragma unroll
    for (int ol = 0; ol < 2; ++ol) {
      float scale = scl[o0 + ol - obase], shift = shl[o0 + ol - obase];
      float mxv[4], ctv[4];
      #pragma unroll
      for (int bt = 0; bt < 4; ++bt) {
        float h2b = __shfl(acc[2*ol+1][bt][0], 16 + col);
        float mxa = acc[2*ol][bt][0], mna = acc[2*ol][bt][0];
        #pragma unroll
        for (int qq = 1; qq < 4; ++qq) {
          mxa = fmaxf(mxa, acc[2*ol][bt][qq]);
          mna = fminf(mna, acc[2*ol][bt][qq]);
        }
        if (lg == 0) {
          #pragma unroll
          for (int qq = 0; qq < 4; ++qq) {
            mxa = fmaxf(mxa, acc[2*ol+1][bt][qq]);
            mna = fminf(mna, acc[2*ol+1][bt][qq]);
          }
        }
        mxa = fmaxf(mxa, __shfl_xor(mxa, 16));
        mna = fminf(mna, __shfl_xor(mna, 16));
        mxa = fmaxf(mxa, __shfl_xor(mxa, 32));
        mna = fminf(mna, __shfl_xor(mna, 32));
        float sel = (scale >= 0.f) ? mxa : mna;
        mxv[bt] = lrelu((sel - h2b)*scale + shift);
        ctv[bt] = lrelu(h2b*scale + shift);
      }
      float vb = (lg == 0) ? mxv[0] : (lg == 1) ? mxv[1] : (lg == 2) ? mxv[2] : mxv[3];
      float vc = (lg == 0) ? ctv[0] : (lg == 1) ? ctv[1] : (lg == 2) ? ctv[2] : ctv[3];
      size_t pbase = (size_t)(o0+ol)*2*C + m0 + q*64 + lane;
      outx[pbase] = vb;
      outx[pbase + C] = vc;
    }
  }
}

// ---- stage-4 edge-conv, bf16 MFMA: pipelined A-loads, sc/sh in LDS, monotone-max epilogue ----
__global__ __launch_bounds__(512, 2) void k_conv4_mfma(const __hip_bfloat16* Abf, const __hip_bfloat16* Xbf,
                                                       const float* sc, const float* sh, float* x4) {
  constexpr int MT = 256;
  __shared__ char Bs[MT*256];          // 64 KB, XOR-swizzled rows
  __shared__ float scl[32], shl[32];
  int t = threadIdx.x, bx = blockIdx.x, byg = blockIdx.y;
  int m0 = bx*MT;
  for (int u = t; u < MT*16; u += 512) {
    int row = u >> 4, k8 = u & 15;
    s16x8 v = *(const s16x8*)(Xbf + ((size_t)(m0+row) << 7) + (k8 << 3));
    *(s16x8*)(Bs + (row << 8) + ((k8 << 4) ^ ((row & 7) << 4))) = v;
  }
  if (t < 32) { scl[t] = sc[byg*32 + t]; shl[t] = sh[byg*32 + t]; }
  __syncthreads();
  int lane = t & 63, w = t >> 6;
  int col = lane & 15, lg = lane >> 4;
  int q = w & 3, pb = w >> 2;
  s16x8 a0[4];
  {
    const __hip_bfloat16* Ab = Abf + ((size_t)((byg*16 + pb)*64) << 7);
    #pragma unroll
    for (int at = 0; at < 4; ++at)
      a0[at] = *(const s16x8*)(Ab + ((size_t)(at*16 + col) << 7) + lg*8);
  }
  for (int it = 0; it < 8; ++it) {
    int by = byg*16 + it*2 + pb;
    const __hip_bfloat16* Ab = Abf + ((size_t)(by*64) << 7);
    f32x4 acc[4][4] = {};
    s16x8 a1[4];
    #pragma unroll
    for (int at = 0; at < 4; ++at)
      a1[at] = *(const s16x8*)(Ab + ((size_t)(at*16 + col) << 7) + 32 + lg*8);
    {
      int kbyte = lg*16;
      s16x8 b[4];
      #pragma unroll
      for (int bt = 0; bt < 4; ++bt) {
        int r = q*64 + bt*16 + col;
        b[bt] = *(const s16x8*)(Bs + (r << 8) + (kbyte ^ ((r & 7) << 4)));
      }
      __builtin_amdgcn_s_setprio(1);
      #pragma unroll
      for (int at = 0; at < 4; ++at)
        #pragma unroll
        for (int bt = 0; bt < 4; ++bt)
          acc[at][bt] = __builtin_amdgcn_mfma_f32_16x16x32_bf16(a0[at], b[bt], acc[at][bt], 0, 0, 0);
      __builtin_amdgcn_s_setprio(0);
    }
    s16x8 a2[4];
    #pragma unroll
    for (int at = 0; at < 4; ++at)
      a2[at] = *(const s16x8*)(Ab + ((size_t)(at*16 + col) << 7) + 64 + lg*8);
    {
      int kbyte = 64 + lg*16;
      s16x8 b[4];
      #pragma unroll
      for (int bt = 0; bt < 4; ++bt) {
        int r = q*64 + bt*16 + col;
        b[bt] = *(const s16x8*)(Bs + (r << 8) + (kbyte ^ ((r & 7) << 4)));
      }
      __builtin_amdgcn_s_setprio(1);
      #pragma unroll
      for (int at = 0; at < 4; ++at)
        #pragma unroll
        for (int bt = 0; bt < 4; ++bt)
          acc[at][bt] = __builtin_amdgcn_mfma_f32_16x16x32_bf16(a1[at], b[bt], acc[at][bt], 0, 0, 0);
      __builtin_amdgcn_s_setprio(0);
    }
    s16x8 a3[4], a0n[4];
    #pragma unroll
    for (int at = 0; at < 4; ++at)
      a3[at] = *(const s16x8*)(Ab + ((size_t)(at*16 + col) << 7) + 96 + lg*8);
    {
      int byN = (it < 7) ? (by + 2) : by;
      const __hip_bfloat16* AbN = Abf + ((size_t)(byN*64) << 7);
      #pragma unroll
      for (int at = 0; at < 4; ++at)
        a0n[at] = *(const s16x8*)(AbN + ((size_t)(at*16 + col) << 7) + lg*8);
    }
    {
      int kbyte = 128 + lg*16;
      s16x8 b[4];
      #pragma unroll
      for (int bt = 0; bt < 4; ++bt) {
        int r = q*64 + bt*16 + col;
        b[bt] = *(const s16x8*)(Bs + (r << 8) + (kbyte ^ ((r & 7) << 4)));
      }
      __builtin_amdgcn_s_setprio(1);
      #pragma unroll
      for (int at = 0; at < 4; ++at)
        #pragma unroll
        for (int bt = 0; bt < 4; ++bt)
          acc[at][bt] = __builtin_amdgcn_mfma_f32_16x16x32_bf16(a2[at], b[bt], acc[at][bt], 0, 0, 0);
      __builtin_amdgcn_s_setprio(0);
    }
    {
      int kbyte = 192 + lg*16;
      s16x8 b[4];
      #pragma unroll
      for (int bt = 0; bt < 4; ++bt) {
        int r = q*64 + bt*16 + col;
        b[bt] = *(const s16x8*)(Bs + (r << 8) + (kbyte ^ ((r & 7) << 4)));
      }
      __builtin_amdgcn_s_setprio(1);
      #pragma unroll
      for (int at = 0; at < 4; ++at)
        #pragma unroll
        for (int bt = 0; bt < 4; ++bt)
          acc[at][bt] = __builtin_amdgcn_mfma_f32_16x16x32_bf16(a3[at], b[bt], acc[at][bt], 0, 0, 0);
      __builtin_amdgcn_s_setprio(0);
    }
    // monotone-max epilogue
    int o0 = by*2;
    int sbase = it*4 + pb*2;
    #pragma unroll
    for (int ol = 0; ol < 2; ++ol) {
      float scale = scl[sbase + ol], shift = shl[sbase + ol];
      float mxv[4], ctv[4];
      #pragma unroll
      for (int bt = 0; bt < 4; ++bt) {
        float h2b = __shfl(acc[2*ol+1][bt][0], 16 + col);
        float mxa = acc[2*ol][bt][0], mna = acc[2*ol][bt][0];
        #pragma unroll
        for (int qq = 1; qq < 4; ++qq) {
          mxa = fmaxf(mxa, acc[2*ol][bt][qq]);
          mna = fminf(mna, acc[2*ol][bt][qq]);
        }
        if (lg == 0) {
          #pragma unroll
          for (int qq = 0; qq < 4; ++qq) {
            mxa = fmaxf(mxa, acc[2*ol+1][bt][qq]);
            mna = fminf(mna, acc[2*ol+1][bt][qq]);
          }
        }
        mxa = fmaxf(mxa, __shfl_xor(mxa, 16));
        mna = fminf(mna, __shfl_xor(mna, 16));
        mxa = fmaxf(mxa, __shfl_xor(mxa, 32));
        mna = fminf(mna, __shfl_xor(mna, 32));
        float sel = (scale >= 0.f) ? mxa : mna;
        mxv[bt] = lrelu((sel - h2b)*scale + shift);
        ctv[bt] = lrelu(h2b*scale + shift);
      }
      float vb = (lg == 0) ? mxv[0] : (lg == 1) ? mxv[1] : (lg == 2) ? mxv[2] : mxv[3];
      float vc = (lg == 0) ? ctv[0] : (lg == 1) ? ctv[1] : (lg == 2) ? ctv[2] : ctv[3];
      size_t pbase = (size_t)(o0+ol)*32768 + m0 + q*64 + lane;
      x4[pbase] = vb;
      x4[pbase + 16384] = vc;
    }
    #pragma unroll
    for (int at = 0; at < 4; ++at) a0[at] = a0n[at];
  }
}

// ---- stage 5 via bf16 MFMA ----
__global__ __launch_bounds__(256) void k_s5_mfma(const float* x4, const __hip_bfloat16* w5bf,
                                                 const float* sc, const float* sh,
                                                 float* pm, float* ps) {
  __shared__ char smem[8192 + 32768];
  __shared__ float redm[64][4];
  __shared__ float reds[64][4];
  int t = threadIdx.x, bx = blockIdx.x, by = blockIdx.y;
  int p0 = bx*256, o0 = by*64;
  int lane = t & 63, w = t >> 6;
  int lrow = lane & 15, lg = lane >> 4;
  char* As = smem;
  char* Bs = smem + 8192;
  f32x4 acc[4][4] = {};
  for (int c0 = 0; c0 < 256; c0 += 64) {
    for (int u = t; u < 64*8; u += 256) {
      int row = u >> 3, k8 = u & 7;
      s16x8 v = *(const s16x8*)(w5bf + (size_t)(o0+row)*256 + c0 + k8*8);
      *(s16x8*)(As + row*128 + ((k8*16) ^ ((row&7)<<4))) = v;
    }
    #pragma unroll
    for (int i = 0; i < 8; ++i) {
      __hip_bfloat16 tmp[8];
      #pragma unroll
      for (int j = 0; j < 8; ++j)
        tmp[j] = __float2bfloat16(x4[(size_t)(c0 + i*8 + j)*32768 + p0 + t]);
      *(s16x8*)(Bs + t*128 + ((i*16) ^ ((t&7)<<4))) = *(const s16x8*)tmp;
    }
    __syncthreads();
    #pragma unroll
    for (int ksub = 0; ksub < 2; ++ksub) {
      int kbyte = ksub*64 + lg*16;
      s16x8 a[4], b[4];
      #pragma unroll
      for (int rt = 0; rt < 4; ++rt) { int r = rt*16 + lrow; a[rt] = *(const s16x8*)(As + r*128 + (kbyte ^ ((r&7)<<4))); }
      #pragma unroll
      for (int cf = 0; cf < 4; ++cf) { int r = w*64 + cf*16 + lrow; b[cf] = *(const s16x8*)(Bs + r*128 + (kbyte ^ ((r&7)<<4))); }
      #pragma unroll
      for (int rt = 0; rt < 4; ++rt)
        #pragma unroll
        for (int cf = 0; cf < 4; ++cf)
          acc[rt][cf] = __builtin_amdgcn_mfma_f32_16x16x32_bf16(a[rt], b[cf], acc[rt][cf], 0, 0, 0);
    }
    __syncthreads();
  }
  #pragma unroll
  for (int rt = 0; rt < 4; ++rt) {
    #pragma unroll
    for (int q = 0; q < 4; ++q) {
      int ol = rt*16 + lg*4 + q;
      float scale = sc[o0+ol], shift = sh[o0+ol];
      float mx = -FLT_MAX, sm = 0.f;
      #pragma unroll
      for (int cf = 0; cf < 4; ++cf) {
        float h = lrelu(acc[rt][cf][q]*scale + shift);
        mx = fmaxf(mx, h); sm += h;
      }
      #pragma unroll
      for (int off2 = 1; off2 < 16; off2 <<= 1) {
        mx = fmaxf(mx, __shfl_xor(mx, off2));
        sm += __shfl_xor(sm, off2);
      }
      if (lrow == 0) { redm[ol][w] = mx; reds[ol][w] = sm; }
    }
  }
  __syncthreads();
  if (t < 64) {
    float mx = fmaxf(fmaxf(redm[t][0], redm[t][1]), fmaxf(redm[t][2], redm[t][3]));
    float sm = reds[t][0] + reds[t][1] + reds[t][2] + reds[t][3];
    pm[(size_t)(o0 + t)*128 + bx] = mx;
    ps[(size_t)(o0 + t)*128 + bx] = sm;
  }
}

__global__ __launch_bounds__(512) void k_pool(const float* pm, const float* ps, float* z0) {
  int t = threadIdx.x;
  for (int o = t; o < 512; o += 512) {
    float mx = -FLT_MAX, sm = 0.f;
    for (int nt = 0; nt < 128; ++nt) { mx = fmaxf(mx, pm[(size_t)o*128+nt]); sm += ps[(size_t)o*128+nt]; }
    z0[o] = mx;
    z0[512+o] = sm * (1.f/32768.f);
  }
}

__global__ __launch_bounds__(128) void k_fc1(const float* z0, const float* lw1, float* z1) {
  int bx = blockIdx.x, t = threadIdx.x;
  int rl = t >> 4, cl = t & 15;
  int r = bx*8 + rl;
  float acc = 0.f;
  for (int u = 0; u < 64; ++u) {
    int c = cl*64 + u;
    acc += z0[c] * lw1[(size_t)r*1024 + c];
  }
  #pragma unroll
  for (int off = 1; off < 16; off <<= 1) acc += __shfl_xor(acc, off);
  if (cl == 0) z1[r] = lrelu(acc);
}

__global__ __launch_bounds__(128) void k_fc2(const float* z1, const float* lw2,
                                             const float* lb2, float* z2) {
  int bx = blockIdx.x, t = threadIdx.x;
  int rl = t >> 4, cl = t & 15;
  int r = bx*8 + rl;
  float acc = 0.f;
  for (int u = 0; u < 32; ++u) {
    int c = cl*32 + u;
    acc += z1[c] * lw2[(size_t)r*512 + c];
  }
  #pragma unroll
  for (int off = 1; off < 16; off <<= 1) acc += __shfl_xor(acc, off);
  if (cl == 0) z2[r] = lrelu(acc + lb2[r]);
}

__global__ __launch_bounds__(64) void k_fc3(const float* z2, const float* ow,
                                            const float* ob, float* out) {
  __shared__ float lg[11];
  __shared__ float ex[11];
  int t = threadIdx.x;
  if (t < 11) {
    float acc = 0.f;
    for (int c = 0; c < 256; ++c) acc += z2[c] * ow[t*256 + c];
    lg[t] = acc + ob[t];
  }
  __syncthreads();
  if (t < 11) {
    float m = -FLT_MAX;
    for (int r = 0; r < 11; ++r) m = fmaxf(m, lg[r]);
    ex[t] = expf(lg[t] - m);
  }
  __syncthreads();
  if (t < 11) {
    float s = 0.f;
    for (int r = 0; r < 11; ++r) s += ex[r];
    out[t] = ex[t] / s;
  }
}

extern "C" void kernel_launch(void* const* d_in, const int* in_sizes, int n_in,
                              void* d_out, int out_size, void* d_ws, size_t ws_size,
                              hipStream_t stream) {
  auto f = [&](int i) { return (const float*)d_in[i]; };
  float* ws = (float*)d_ws;
  int* idx = (int*)(ws + OFF_IDX);
  float* out = (float*)d_out;

  if (ws_size < WS_NEEDED_BYTES) {
    k_ws_sentinel<<<1, 64, 0, stream>>>(out, (float)(ws_size >> 20));
    return;
  }

  __hip_bfloat16* Abf = (__hip_bfloat16*)(ws + OFF_ABF);
  __hip_bfloat16* Xbf = (__hip_bfloat16*)(ws + OFF_GP);       // after dist4 consumed partials
  __hip_bfloat16* w5bf = (__hip_bfloat16*)(ws + OFF_W5BF);
  float* x4 = ws + OFF_X4;
  __hip_bfloat16* Xh = (__hip_bfloat16*)(ws + OFF_SPLIT);
  __hip_bfloat16* X1L = Xh + 262144;                          // stage-2: x1 hi/lo (64*4096 each)
  __hip_bfloat16* X2L = Xh + 524288;                          // stage-3: x2 hi/lo (64*8192 each)
  __hip_bfloat16* A2H = (__hip_bfloat16*)(ws + OFF_A);
  __hip_bfloat16* A2L = A2H + 131072;                         // 2048*64 each
  __hip_bfloat16* A3H = (__hip_bfloat16*)(ws + OFF_A);
  __hip_bfloat16* A3L = A3H + 262144;                         // 4096*64 each

  k_bn_pre<<<1, 512, 0, stream>>>(f(2),f(3),f(4),f(5), f(7),f(8),f(9),f(10),
                                  f(12),f(13),f(14),f(15), f(17),f(18),f(19),f(20),
                                  f(22),f(23),f(24),f(25), ws);
  // stage 1 (4 waves/block register top-k; hierarchical group maxima)
  k_s1_topk<<<N/4, 256, 0, stream>>>(f(0), idx);
  k_s1_conv<<<dim3(N/64, 16), 256, 0, stream>>>(f(0), f(1), idx, ws+OFF_SC1, ws+OFF_SH1, ws+OFF_X1);
  // stage 2: prev=x1 (M=4096,P=64,O=64) — kNN f32, conv bf16x3 MFMA
  k_gram_partial<64><<<64, 256, 0, stream>>>(ws+OFF_X1, 4096, ws+OFF_GP);
  k_dist_topk<64><<<64, 128, 0, stream>>>(ws+OFF_GP, idx, 64);
  k_build_A_bf32<<<32, 64, 0, stream>>>(f(6), idx, A2H, A2L);
  k_split_bf16x2<<<256, 256, 0, stream>>>(ws+OFF_X1, Xh, X1L);
  k_fconv_mfma<<<dim3(16, 8), 512, 0, stream>>>(A2H, A2L, Xh, X1L, ws+OFF_SC2, ws+OFF_SH2, 4096, 2, ws+OFF_X2);
  // stage 3: prev=x2 (M=8192,P=64,O=128)
  k_gram_partial<64><<<64, 256, 0, stream>>>(ws+OFF_X2, 8192, ws+OFF_GP);
  k_dist_topk<64><<<64, 128, 0, stream>>>(ws+OFF_GP, idx, 64);
  k_build_A_bf32<<<64, 64, 0, stream>>>(f(11), idx, A3H, A3L);
  k_split_bf16x2<<<512, 256, 0, stream>>>(ws+OFF_X2, Xh, X2L);
  k_fconv_mfma<<<dim3(32, 8), 512, 0, stream>>>(A3H, A3L, Xh, X2L, ws+OFF_SC3, ws+OFF_SH3, 8192, 4, ws+OFF_X3);
  // stage 4: prev=x3 (M=16384,P=128,O=256) — kNN f32, conv bf16 MFMA
  k_gram_partial<128><<<64, 256, 0, stream>>>(ws+OFF_X3, 16384, ws+OFF_GP);
  k_dist_topk<128><<<128, 128, 0, stream>>>(ws+OFF_GP, idx, 64);
  k_build_A_bf<<<128, 64, 0, stream>>>(f(16), idx, Abf);
  k_f32_to_bf16<<<512, 256, 0, stream>>>(ws+OFF_X3, Xbf);
  k_conv4_mfma<<<dim3(16384/256, 8), 512, 0, stream>>>(Abf, Xbf, ws+OFF_SC4, ws+OFF_SH4, x4);
  // stage 5 (bf16 MFMA, pooling fused) + head
  k_f32_to_bf16<<<32, 256, 0, stream>>>(f(21), w5bf);
  k_s5_mfma<<<dim3(128, 8), 256, 0, stream>>>(x4, w5bf, ws+OFF_SC5, ws+OFF_SH5, ws+OFF_PM, ws+OFF_PS);
  k_pool<<<1, 512, 0, stream>>>(ws+OFF_PM, ws+OFF_PS, ws+OFF_Z0);
  k_fc1<<<64, 128, 0, stream>>>(ws+OFF_Z0, f(26), ws+OFF_Z1);
  k_fc2<<<32, 128, 0, stream>>>(ws+OFF_Z1, f(27), f(28), ws+OFF_Z2);
  k_fc3<<<1, 64, 0, stream>>>(ws+OFF_Z2, f(29), f(30), out);
}